// Round 1
// baseline (242.635 us; speedup 1.0000x reference)
//
#include <hip/hip_runtime.h>
#include <hip/hip_bf16.h>
#include <math.h>

#define B_  4
#define T_  1024
#define C_  1024
#define H_  16
#define D_  64
#define NEG (-1e30f)

typedef __attribute__((ext_vector_type(8))) __bf16 bf16x8;
typedef __attribute__((ext_vector_type(4))) __bf16 bf16x4;
typedef __attribute__((ext_vector_type(4))) float f32x4;

#define MFMA16(a,b,c) __builtin_amdgcn_mfma_f32_16x16x32_bf16(a,b,c,0,0,0)

__device__ __forceinline__ bf16x8 cvt8(float4 a, float4 b){
  bf16x8 v;
  v[0]=(__bf16)a.x; v[1]=(__bf16)a.y; v[2]=(__bf16)a.z; v[3]=(__bf16)a.w;
  v[4]=(__bf16)b.x; v[5]=(__bf16)b.y; v[6]=(__bf16)b.z; v[7]=(__bf16)b.w;
  return v;
}

// ---------------------------------------------------------------------------
// Kernel 1: log-mask table LM[h][rel] (rel in [0,T)) + span_loss scalar.
// mask depends only on (h, q-k): huge collapse from [H,T,T] to [H,T].
// dead (incl. clip boundary) -> NEG sentinel; causality handled in attn.
// ---------------------------------------------------------------------------
__global__ void lm_kernel(const float* __restrict__ sp, const float* __restrict__ pw,
                          const float* __restrict__ rw, float* __restrict__ LM,
                          float* __restrict__ loss_out) {
  const int h = blockIdx.x, t = threadIdx.x;
  const float PI = 3.14159265358979323846f;
  float s      = 1024.f / (1.f + expf(-sp[h]));
  float period = 2.f + 62.f / (1.f + expf(-pw[h]));
  float ratio  = -0.25f + 0.5f / (1.f + expf(-rw[h]));
  float amp    = 0.25f * period;
  float offset = period * ratio;
  float c1 = 16.f/(PI*PI), c3 = c1/9.f, c5 = c1/25.f;
  #pragma unroll
  for (int i = 0; i < 4; ++i) {
    int rel = t + i*256;
    float ms = fminf(fmaxf((32.f - (float)rel + s) / 32.f, 0.f), 1.f);
    float ph = fmodf(2.f*PI*(float)rel/period, 2.f*PI);
    float wv = c1*cosf(ph) + c3*cosf(3.f*ph) + c5*cosf(5.f*ph);
    wv = wv*amp*0.5f + 0.5f + offset;
    wv = fminf(fmaxf(wv, 0.f), 1.f);
    float v;
    if (fminf(ms, wv) <= 1e-6f) v = NEG;
    else v = logf(fmaxf(ms,1e-6f)) + logf(fmaxf(wv,1e-6f));
    LM[h*T_ + rel] = v;
  }
  if (h == 0 && t == 0) {
    float acc = 0.f;
    for (int hh = 0; hh < H_; ++hh) {
      float s2      = 1024.f / (1.f + expf(-sp[hh]));
      float period2 = 2.f + 62.f / (1.f + expf(-pw[hh]));
      float ratio2  = -0.25f + 0.5f / (1.f + expf(-rw[hh]));
      float amp2    = 0.25f * period2;
      float off2    = period2 * ratio2;
      float base = 1.f/period2 + 2.f*ratio2 + 0.5f;
      float lt = base < 1.f ? base : 1.f + (0.5f + off2 - amp2);
      acc += (s2 + 32.f) * lt;
    }
    *loss_out = 1e-4f * acc / (float)H_;
  }
}

// ---------------------------------------------------------------------------
// Kernel 2: transpose + fp32->bf16 convert: in [K][N] f32 -> out [N][K] bf16
// (weights become [N][K] so GEMM B-fragments load identically to A-fragments)
// ---------------------------------------------------------------------------
__global__ __launch_bounds__(256) void transpose_cvt(const float* __restrict__ in,
                                                     __bf16* __restrict__ out,
                                                     int K, int N) {
  __shared__ __bf16 tile[64][72];
  const int n0 = blockIdx.x*64, k0 = blockIdx.y*64;
  const int t = threadIdx.x, r = t >> 4, c4 = (t & 15) * 4;
  #pragma unroll
  for (int rr = 0; rr < 64; rr += 16) {
    float4 v = *(const float4*)&in[(size_t)(k0 + r + rr)*N + n0 + c4];
    tile[r+rr][c4+0] = (__bf16)v.x; tile[r+rr][c4+1] = (__bf16)v.y;
    tile[r+rr][c4+2] = (__bf16)v.z; tile[r+rr][c4+3] = (__bf16)v.w;
  }
  __syncthreads();
  #pragma unroll
  for (int rr = 0; rr < 64; rr += 16) {
    bf16x4 ov;
    ov[0] = tile[c4+0][r+rr]; ov[1] = tile[c4+1][r+rr];
    ov[2] = tile[c4+2][r+rr]; ov[3] = tile[c4+3][r+rr];
    *(bf16x4*)&out[(size_t)(n0 + r + rr)*K + k0 + c4] = ov;
  }
}

// ---------------------------------------------------------------------------
// Kernel 3: 128x128 tile bf16 MFMA GEMM, Bt input is [N][K] bf16.
// A_FP32: A is fp32, converted during LDS staging (QKV path: A = x).
// MODE 0: epilogue scatters q,k -> [B,H,T,D] bf16; v -> transposed [B,H,D,T].
// MODE 1: epilogue writes fp32 [M][N] to outf.
// ---------------------------------------------------------------------------
template<int A_FP32, int MODE>
__global__ __launch_bounds__(256) void gemm_bt(
    const void* __restrict__ Av, const __bf16* __restrict__ Bt,
    int M, int N, int K,
    __bf16* __restrict__ q_bf, __bf16* __restrict__ k_bf,
    __bf16* __restrict__ vt_bf, float* __restrict__ outf)
{
  __shared__ __align__(16) __bf16 As[128*32];
  __shared__ __align__(16) __bf16 Bs[128*32];

  const int t = threadIdx.x;
  const int m0 = blockIdx.y * 128, n0 = blockIdx.x * 128;
  const int lane = t & 63, w = t >> 6, quad = lane >> 4, lr = lane & 15;
  const int wm = (w >> 1) * 64, wn = (w & 1) * 64;
  const int srow = t >> 2, scol = (t & 3) * 8;

  const float* A32 = (const float*)Av;
  const __bf16* A16 = (const __bf16*)Av;

  f32x4 acc[4][4];
  const f32x4 fz = {0.f, 0.f, 0.f, 0.f};
  #pragma unroll
  for (int mi = 0; mi < 4; ++mi)
    #pragma unroll
    for (int ni = 0; ni < 4; ++ni) acc[mi][ni] = fz;

  auto loadA = [&](int kt, int rr) -> bf16x8 {
    size_t off = (size_t)(m0 + srow + rr)*K + kt*32 + scol;
    if constexpr (A_FP32 == 1) {
      float4 u0 = *(const float4*)(A32 + off);
      float4 u1 = *(const float4*)(A32 + off + 4);
      return cvt8(u0, u1);
    } else {
      return *(const bf16x8*)(A16 + off);
    }
  };
  auto loadB = [&](int kt, int rr) -> bf16x8 {
    return *(const bf16x8*)(Bt + (size_t)(n0 + srow + rr)*K + kt*32 + scol);
  };

  bf16x8 pa0 = loadA(0, 0), pa1 = loadA(0, 64);
  bf16x8 pb0 = loadB(0, 0), pb1 = loadB(0, 64);

  const int nk = K >> 5;
  for (int kt = 0; kt < nk; ++kt) {
    __syncthreads();
    *(bf16x8*)&As[srow*32 + scol]      = pa0;
    *(bf16x8*)&As[(srow+64)*32 + scol] = pa1;
    *(bf16x8*)&Bs[srow*32 + scol]      = pb0;
    *(bf16x8*)&Bs[(srow+64)*32 + scol] = pb1;
    __syncthreads();
    if (kt + 1 < nk) {
      pa0 = loadA(kt+1, 0); pa1 = loadA(kt+1, 64);
      pb0 = loadB(kt+1, 0); pb1 = loadB(kt+1, 64);
    }
    bf16x8 af[4], bfr[4];
    #pragma unroll
    for (int mi = 0; mi < 4; ++mi)
      af[mi] = *(const bf16x8*)&As[(wm + mi*16 + lr)*32 + quad*8];
    #pragma unroll
    for (int ni = 0; ni < 4; ++ni)
      bfr[ni] = *(const bf16x8*)&Bs[(wn + ni*16 + lr)*32 + quad*8];
    #pragma unroll
    for (int mi = 0; mi < 4; ++mi)
      #pragma unroll
      for (int ni = 0; ni < 4; ++ni)
        acc[mi][ni] = MFMA16(af[mi], bfr[ni], acc[mi][ni]);
  }

  // ---- epilogue (C/D layout: col = lane&15, row = quad*4 + reg) ----
  if constexpr (MODE == 0) {
    #pragma unroll
    for (int mi = 0; mi < 4; ++mi) {
      int mg = m0 + wm + mi*16 + quad*4;
      int b  = mg >> 10, tl = mg & 1023;
      #pragma unroll
      for (int ni = 0; ni < 4; ++ni) {
        int ng = n0 + wn + ni*16 + lr;
        int part = ng >> 10, c = ng & 1023, h = c >> 6, d = c & 63;
        if (part == 2) {
          bf16x4 pk;
          pk[0] = (__bf16)acc[mi][ni][0]; pk[1] = (__bf16)acc[mi][ni][1];
          pk[2] = (__bf16)acc[mi][ni][2]; pk[3] = (__bf16)acc[mi][ni][3];
          *(bf16x4*)&vt_bf[(((size_t)(b*H_ + h)*D_ + d) << 10) + tl] = pk;
        } else {
          __bf16* dst = (part == 0) ? q_bf : k_bf;
          size_t base = (size_t)(b*H_ + h) * T_;
          #pragma unroll
          for (int r = 0; r < 4; ++r)
            dst[(base + tl + r)*D_ + d] = (__bf16)acc[mi][ni][r];
        }
      }
    }
  } else {
    #pragma unroll
    for (int mi = 0; mi < 4; ++mi) {
      int mg = m0 + wm + mi*16 + quad*4;
      #pragma unroll
      for (int r = 0; r < 4; ++r) {
        float* orow = outf + (size_t)(mg + r)*N + n0 + wn;
        #pragma unroll
        for (int ni = 0; ni < 4; ++ni)
          orow[ni*16 + lr] = acc[mi][ni][r];
      }
    }
  }
}

// ---------------------------------------------------------------------------
// Kernel 4: flash attention with the collapsed [H,T] log-mask.
// 1 block = (b, h, 64 q-rows); 1 wave = 16 q-rows, K-tiles of 64 keys.
// Online softmax with NEG sentinel (dead-tile garbage self-flushes: alpha=0).
// P goes C-layout -> A-layout via per-wave LDS round-trip (no barriers;
// wave-local lgkmcnt(0) since waves have divergent trip counts).
// ---------------------------------------------------------------------------
__global__ __launch_bounds__(256) void attn_kernel(
    const __bf16* __restrict__ q_bf, const __bf16* __restrict__ k_bf,
    const __bf16* __restrict__ vt_bf, const float* __restrict__ LM,
    const float* __restrict__ sp, __bf16* __restrict__ yatt)
{
  __shared__ float lm_s[T_];
  __shared__ __align__(16) __bf16 p_s[4][16*72];

  const int bh = blockIdx.y, b = bh >> 4, h = bh & 15;
  const int q0b = blockIdx.x * 64;
  const int t = threadIdx.x, w = t >> 6, lane = t & 63, quad = lane >> 4, lr = lane & 15;

  ((float4*)lm_s)[t] = ((const float4*)(LM + (size_t)h*T_))[t];
  __syncthreads();

  const int q0w = q0b + w*16;
  const __bf16* Q  = q_bf  + (size_t)bh * T_ * D_;
  const __bf16* Km = k_bf  + (size_t)bh * T_ * D_;
  const __bf16* Vt = vt_bf + (size_t)bh * D_ * T_;

  bf16x8 aq0 = *(const bf16x8*)&Q[(q0w + lr)*D_ + quad*8];
  bf16x8 aq1 = *(const bf16x8*)&Q[(q0w + lr)*D_ + 32 + quad*8];

  const f32x4 fz = {0.f,0.f,0.f,0.f};
  f32x4 o[4]; float m_r[4], l_r[4];
  #pragma unroll
  for (int i = 0; i < 4; ++i) { o[i] = fz; m_r[i] = NEG; l_r[i] = 0.f; }

  // conservative skip of fully-dead K-tiles (rel >= R + span): only a
  // perf opt — skipped tiles are exactly the NEG-table tiles.
  float s_h = 1024.f / (1.f + expf(-sp[h]));
  int kdead = (int)floorf((float)q0w - 33.0f - s_h);  // -1 safety margin
  int kt0 = (kdead + 1) > 0 ? (kdead + 1) >> 6 : 0;
  const int ktlast = (q0w + 15) >> 6;
  const float scale = 0.125f;  // 1/sqrt(64)

  for (int kt = kt0; kt <= ktlast; ++kt) {
    const int kb = kt * 64;
    f32x4 sacc[4];
    #pragma unroll
    for (int ni = 0; ni < 4; ++ni) {
      bf16x8 bk0 = *(const bf16x8*)&Km[(kb + ni*16 + lr)*D_ + quad*8];
      bf16x8 bk1 = *(const bf16x8*)&Km[(kb + ni*16 + lr)*D_ + 32 + quad*8];
      sacc[ni] = MFMA16(aq0, bk0, fz);
      sacc[ni] = MFMA16(aq1, bk1, sacc[ni]);
    }
    // mask + online softmax
    float lg[4][4];
    float mx[4] = {NEG, NEG, NEG, NEG};
    #pragma unroll
    for (int ni = 0; ni < 4; ++ni) {
      int kg = kb + ni*16 + lr;
      #pragma unroll
      for (int r = 0; r < 4; ++r) {
        int qg = q0w + quad*4 + r;
        int rel = qg - kg;
        float v = (rel >= 0) ? sacc[ni][r]*scale + lm_s[rel] : NEG;
        lg[ni][r] = v;
        mx[r] = fmaxf(mx[r], v);
      }
    }
    #pragma unroll
    for (int off = 1; off < 16; off <<= 1)
      #pragma unroll
      for (int r = 0; r < 4; ++r)
        mx[r] = fmaxf(mx[r], __shfl_xor(mx[r], off, 64));
    float alpha[4], rs[4] = {0.f,0.f,0.f,0.f};
    #pragma unroll
    for (int r = 0; r < 4; ++r) {
      float mn = fmaxf(m_r[r], mx[r]);
      alpha[r] = __expf(m_r[r] - mn);   // NEG-NEG -> exp(0)=1 (self-flushing)
      m_r[r] = mn;
    }
    #pragma unroll
    for (int ni = 0; ni < 4; ++ni)
      #pragma unroll
      for (int r = 0; r < 4; ++r) {
        float p = __expf(lg[ni][r] - m_r[r]);
        rs[r] += p;
        p_s[w][(quad*4 + r)*72 + ni*16 + lr] = (__bf16)p;
      }
    #pragma unroll
    for (int off = 1; off < 16; off <<= 1)
      #pragma unroll
      for (int r = 0; r < 4; ++r)
        rs[r] += __shfl_xor(rs[r], off, 64);
    #pragma unroll
    for (int r = 0; r < 4; ++r) l_r[r] = l_r[r]*alpha[r] + rs[r];
    #pragma unroll
    for (int ni = 0; ni < 4; ++ni)
      #pragma unroll
      for (int r = 0; r < 4; ++r) o[ni][r] *= alpha[r];

    asm volatile("s_waitcnt lgkmcnt(0)" ::: "memory");  // P writes visible to this wave
    bf16x8 ap0 = *(const bf16x8*)&p_s[w][lr*72 + quad*8];
    bf16x8 ap1 = *(const bf16x8*)&p_s[w][lr*72 + 32 + quad*8];
    #pragma unroll
    for (int ni = 0; ni < 4; ++ni) {
      bf16x8 bv0 = *(const bf16x8*)&Vt[(ni*16 + lr)*T_ + kb + quad*8];
      bf16x8 bv1 = *(const bf16x8*)&Vt[(ni*16 + lr)*T_ + kb + 32 + quad*8];
      o[ni] = MFMA16(ap0, bv0, o[ni]);
      o[ni] = MFMA16(ap1, bv1, o[ni]);
    }
    asm volatile("s_waitcnt lgkmcnt(0)" ::: "memory");  // P reads done before next overwrite
  }

  // epilogue: O/l -> yatt [B][T][C] bf16 (C index = h*64 + d)
  #pragma unroll
  for (int ni = 0; ni < 4; ++ni)
    #pragma unroll
    for (int r = 0; r < 4; ++r) {
      int qg = q0w + quad*4 + r;
      float v = o[ni][r] / l_r[r];
      yatt[((size_t)(b*T_ + qg))*C_ + h*D_ + ni*16 + lr] = (__bf16)v;
    }
}

// ---------------------------------------------------------------------------
extern "C" void kernel_launch(void* const* d_in, const int* in_sizes, int n_in,
                              void* d_out, int out_size, void* d_ws, size_t ws_size,
                              hipStream_t stream) {
  const float* x     = (const float*)d_in[0];
  const float* Wqkv  = (const float*)d_in[1];
  const float* Wproj = (const float*)d_in[2];
  const float* sp    = (const float*)d_in[3];
  const float* pw    = (const float*)d_in[4];
  const float* rw    = (const float*)d_in[5];
  float* out = (float*)d_out;

  char* ws = (char*)d_ws;
  size_t off = 0;
  auto alloc = [&](size_t bytes) -> void* {
    void* p = ws + off;
    off += (bytes + 255) & ~(size_t)255;
    return p;
  };
  float*  LM     = (float*) alloc((size_t)H_*T_*4);
  __bf16* wqkv_t = (__bf16*)alloc((size_t)3*C_*C_*2);
  __bf16* wp_t   = (__bf16*)alloc((size_t)C_*C_*2);
  __bf16* q_bf   = (__bf16*)alloc((size_t)B_*H_*T_*D_*2);
  __bf16* k_bf   = (__bf16*)alloc((size_t)B_*H_*T_*D_*2);
  __bf16* vt_bf  = (__bf16*)alloc((size_t)B_*H_*T_*D_*2);
  __bf16* yatt   = (__bf16*)alloc((size_t)B_*T_*C_*2);

  lm_kernel<<<H_, 256, 0, stream>>>(sp, pw, rw, LM, out + (out_size - 1));
  transpose_cvt<<<dim3(3*C_/64, C_/64), 256, 0, stream>>>(Wqkv, wqkv_t, C_, 3*C_);
  transpose_cvt<<<dim3(C_/64,   C_/64), 256, 0, stream>>>(Wproj, wp_t, C_, C_);
  gemm_bt<1,0><<<dim3(3*C_/128, (B_*T_)/128), 256, 0, stream>>>(
      x, wqkv_t, B_*T_, 3*C_, C_, q_bf, k_bf, vt_bf, nullptr);
  attn_kernel<<<dim3(T_/64, B_*H_), 256, 0, stream>>>(q_bf, k_bf, vt_bf, LM, sp, yatt);
  gemm_bt<0,1><<<dim3(C_/128, (B_*T_)/128), 256, 0, stream>>>(
      yatt, wp_t, B_*T_, C_, C_, nullptr, nullptr, nullptr, out);
}

// Round 2
// 224.225 us; speedup vs baseline: 1.0821x; 1.0821x over previous
//
#include <hip/hip_runtime.h>
#include <hip/hip_bf16.h>
#include <math.h>

#define B_  4
#define T_  1024
#define C_  1024
#define H_  16
#define D_  64
#define NEG (-1e30f)

typedef __attribute__((ext_vector_type(8))) __bf16 bf16x8;
typedef __attribute__((ext_vector_type(4))) __bf16 bf16x4;
typedef __attribute__((ext_vector_type(4))) float f32x4;

#define MFMA16(a,b,c) __builtin_amdgcn_mfma_f32_16x16x32_bf16(a,b,c,0,0,0)

__device__ __forceinline__ bf16x8 cvt8(float4 a, float4 b){
  bf16x8 v;
  v[0]=(__bf16)a.x; v[1]=(__bf16)a.y; v[2]=(__bf16)a.z; v[3]=(__bf16)a.w;
  v[4]=(__bf16)b.x; v[5]=(__bf16)b.y; v[6]=(__bf16)b.z; v[7]=(__bf16)b.w;
  return v;
}

__device__ __forceinline__ void gll16(const __bf16* g, __bf16* l) {
  __builtin_amdgcn_global_load_lds(
      (const __attribute__((address_space(1))) void*)g,
      (__attribute__((address_space(3))) void*)l, 16, 0, 0);
}

// ---------------------------------------------------------------------------
// Kernel 1: log2-domain mask table LM2[h][rel] = log2e*(log ms + log wv),
// dead -> NEG sentinel. Also writes span_loss scalar.
// ---------------------------------------------------------------------------
__global__ void lm_kernel(const float* __restrict__ sp, const float* __restrict__ pw,
                          const float* __restrict__ rw, float* __restrict__ LM,
                          float* __restrict__ loss_out) {
  const int h = blockIdx.x, t = threadIdx.x;
  const float PI = 3.14159265358979323846f;
  float s      = 1024.f / (1.f + expf(-sp[h]));
  float period = 2.f + 62.f / (1.f + expf(-pw[h]));
  float ratio  = -0.25f + 0.5f / (1.f + expf(-rw[h]));
  float amp    = 0.25f * period;
  float offset = period * ratio;
  float c1 = 16.f/(PI*PI), c3 = c1/9.f, c5 = c1/25.f;
  #pragma unroll
  for (int i = 0; i < 4; ++i) {
    int rel = t + i*256;
    float ms = fminf(fmaxf((32.f - (float)rel + s) / 32.f, 0.f), 1.f);
    float ph = fmodf(2.f*PI*(float)rel/period, 2.f*PI);
    float wv = c1*cosf(ph) + c3*cosf(3.f*ph) + c5*cosf(5.f*ph);
    wv = wv*amp*0.5f + 0.5f + offset;
    wv = fminf(fmaxf(wv, 0.f), 1.f);
    float v;
    if (fminf(ms, wv) <= 1e-6f) v = NEG;
    else v = log2f(fmaxf(ms,1e-6f)) + log2f(fmaxf(wv,1e-6f));  // log2 domain
    LM[h*T_ + rel] = v;
  }
  if (h == 0 && t == 0) {
    float acc = 0.f;
    for (int hh = 0; hh < H_; ++hh) {
      float s2      = 1024.f / (1.f + expf(-sp[hh]));
      float period2 = 2.f + 62.f / (1.f + expf(-pw[hh]));
      float ratio2  = -0.25f + 0.5f / (1.f + expf(-rw[hh]));
      float amp2    = 0.25f * period2;
      float off2    = period2 * ratio2;
      float base = 1.f/period2 + 2.f*ratio2 + 0.5f;
      float lt = base < 1.f ? base : 1.f + (0.5f + off2 - amp2);
      acc += (s2 + 32.f) * lt;
    }
    *loss_out = 1e-4f * acc / (float)H_;
  }
}

// ---------------------------------------------------------------------------
// Kernel 2: transpose + fp32->bf16: in [K][N] f32 -> out [N][K] bf16
// ---------------------------------------------------------------------------
__global__ __launch_bounds__(256) void transpose_cvt(const float* __restrict__ in,
                                                     __bf16* __restrict__ out,
                                                     int K, int N) {
  __shared__ __bf16 tile[64][72];
  const int n0 = blockIdx.x*64, k0 = blockIdx.y*64;
  const int t = threadIdx.x, r = t >> 4, c4 = (t & 15) * 4;
  #pragma unroll
  for (int rr = 0; rr < 64; rr += 16) {
    float4 v = *(const float4*)&in[(size_t)(k0 + r + rr)*N + n0 + c4];
    tile[r+rr][c4+0] = (__bf16)v.x; tile[r+rr][c4+1] = (__bf16)v.y;
    tile[r+rr][c4+2] = (__bf16)v.z; tile[r+rr][c4+3] = (__bf16)v.w;
  }
  __syncthreads();
  #pragma unroll
  for (int rr = 0; rr < 64; rr += 16) {
    bf16x4 ov;
    ov[0] = tile[c4+0][r+rr]; ov[1] = tile[c4+1][r+rr];
    ov[2] = tile[c4+2][r+rr]; ov[3] = tile[c4+3][r+rr];
    *(bf16x4*)&out[(size_t)(n0 + r + rr)*K + k0 + c4] = ov;
  }
}

// ---------------------------------------------------------------------------
// Kernel 3: fp32 -> bf16 bulk convert (x -> x_bf), 8 elements/thread
// ---------------------------------------------------------------------------
__global__ __launch_bounds__(256) void cvt_kernel(const float* __restrict__ in,
                                                  __bf16* __restrict__ out) {
  size_t i = ((size_t)blockIdx.x*256 + threadIdx.x) * 8;
  float4 a = *(const float4*)(in + i);
  float4 b = *(const float4*)(in + i + 4);
  *(bf16x8*)(out + i) = cvt8(a, b);
}

// ---------------------------------------------------------------------------
// Kernel 4: 128x128 bf16 MFMA GEMM, m97 structure (global_load_lds x16).
// A [M][K] bf16, Bt [N][K] bf16.
// MODE 0: scatter q,k -> [B,H,T,D]; v -> [B,H,D,T].  MODE 1: fp32 [M][N].
// ---------------------------------------------------------------------------
template<int MODE>
__global__ __launch_bounds__(256) void gemm_bt(
    const __bf16* __restrict__ A, const __bf16* __restrict__ Bt,
    int M, int N, int K,
    __bf16* __restrict__ q_bf, __bf16* __restrict__ k_bf,
    __bf16* __restrict__ vt_bf, float* __restrict__ outf)
{
  __shared__ __align__(16) __bf16 As[128*32];
  __shared__ __align__(16) __bf16 Bs[128*32];

  const int t = threadIdx.x;
  const int m0 = blockIdx.y * 128, n0 = blockIdx.x * 128;
  const int lane = t & 63, w = t >> 6, quad = lane >> 4, lr = lane & 15;
  const int wm = (w >> 1) * 64, wn = (w & 1) * 64;
  const int srow = t >> 2, scol = (t & 3) * 8;

  const __bf16* gA = A  + (size_t)(m0 + srow)*K + scol;
  const __bf16* gB = Bt + (size_t)(n0 + srow)*K + scol;
  __bf16* lA0 = As + w*512;          // wave-uniform LDS dest (lane*16B apart)
  __bf16* lA1 = As + 64*32 + w*512;
  __bf16* lB0 = Bs + w*512;
  __bf16* lB1 = Bs + 64*32 + w*512;

  f32x4 acc[4][4];
  const f32x4 fz = {0.f, 0.f, 0.f, 0.f};
  #pragma unroll
  for (int mi = 0; mi < 4; ++mi)
    #pragma unroll
    for (int ni = 0; ni < 4; ++ni) acc[mi][ni] = fz;

  const int nk = K >> 5;
  for (int kt = 0; kt < nk; ++kt) {
    __syncthreads();
    gll16(gA + kt*32,              lA0);
    gll16(gA + (size_t)64*K + kt*32, lA1);
    gll16(gB + kt*32,              lB0);
    gll16(gB + (size_t)64*K + kt*32, lB1);
    __syncthreads();
    bf16x8 af[4], bfr[4];
    #pragma unroll
    for (int mi = 0; mi < 4; ++mi)
      af[mi] = *(const bf16x8*)&As[(wm + mi*16 + lr)*32 + quad*8];
    #pragma unroll
    for (int ni = 0; ni < 4; ++ni)
      bfr[ni] = *(const bf16x8*)&Bs[(wn + ni*16 + lr)*32 + quad*8];
    #pragma unroll
    for (int mi = 0; mi < 4; ++mi)
      #pragma unroll
      for (int ni = 0; ni < 4; ++ni)
        acc[mi][ni] = MFMA16(af[mi], bfr[ni], acc[mi][ni]);
  }

  if constexpr (MODE == 0) {
    #pragma unroll
    for (int mi = 0; mi < 4; ++mi) {
      int mg = m0 + wm + mi*16 + quad*4;
      int b  = mg >> 10, tl = mg & 1023;
      #pragma unroll
      for (int ni = 0; ni < 4; ++ni) {
        int ng = n0 + wn + ni*16 + lr;
        int part = ng >> 10, c = ng & 1023, h = c >> 6, d = c & 63;
        if (part == 2) {
          bf16x4 pk;
          pk[0] = (__bf16)acc[mi][ni][0]; pk[1] = (__bf16)acc[mi][ni][1];
          pk[2] = (__bf16)acc[mi][ni][2]; pk[3] = (__bf16)acc[mi][ni][3];
          *(bf16x4*)&vt_bf[(((size_t)(b*H_ + h)*D_ + d) << 10) + tl] = pk;
        } else {
          __bf16* dst = (part == 0) ? q_bf : k_bf;
          size_t base = (size_t)(b*H_ + h) * T_;
          #pragma unroll
          for (int r = 0; r < 4; ++r)
            dst[(base + tl + r)*D_ + d] = (__bf16)acc[mi][ni][r];
        }
      }
    }
  } else {
    #pragma unroll
    for (int mi = 0; mi < 4; ++mi) {
      int mg = m0 + wm + mi*16 + quad*4;
      #pragma unroll
      for (int r = 0; r < 4; ++r) {
        float* orow = outf + (size_t)(mg + r)*N + n0 + wn;
        #pragma unroll
        for (int ni = 0; ni < 4; ++ni)
          orow[ni*16 + lr] = acc[mi][ni][r];
      }
    }
  }
}

// ---------------------------------------------------------------------------
// Kernel 5: flash attention, fixed-base softmax (no running max/rescale):
// scores are bounded (|qk/8| ~ 5, fp32 exp safe to 88) -> p = exp2(qk*s2 +
// LM2[rel]) directly; l accumulated per-lane, reduced ONCE at the end.
// 1 wave per block, 16 q-rows, 128-key tiles. Table has 128-entry NEG
// prefix so causality needs no branch (exp2(-1e30)=0 self-masks).
// ---------------------------------------------------------------------------
__global__ __launch_bounds__(64, 4) void attn_kernel(
    const __bf16* __restrict__ q_bf, const __bf16* __restrict__ k_bf,
    const __bf16* __restrict__ vt_bf, const float* __restrict__ LM,
    const float* __restrict__ sp, __bf16* __restrict__ yatt)
{
  __shared__ float lm_s[1152];               // [0,128)=NEG, [128+rel]=LM2
  __shared__ __align__(16) __bf16 p_s[16*136];

  const int bh = blockIdx.x, b = bh >> 4, h = bh & 15;
  const int qt = 63 - blockIdx.y;            // longest-work blocks first
  const int q0w = qt * 16;
  const int lane = threadIdx.x, quad = lane >> 4, lr = lane & 15;

  #pragma unroll
  for (int i = 0; i < 2; ++i) lm_s[lane + i*64] = NEG;
  {
    const float4* src = (const float4*)(LM + (size_t)h*T_);
    #pragma unroll
    for (int i = 0; i < 4; ++i)
      ((float4*)(lm_s + 128))[lane + i*64] = src[lane + i*64];
  }
  asm volatile("s_waitcnt lgkmcnt(0)" ::: "memory");

  const __bf16* Q  = q_bf  + (size_t)bh * (T_*D_);
  const __bf16* Km = k_bf  + (size_t)bh * (T_*D_);
  const __bf16* Vt = vt_bf + (size_t)bh * (D_*T_);

  bf16x8 aq0 = *(const bf16x8*)&Q[(q0w + lr)*D_ + quad*8];
  bf16x8 aq1 = *(const bf16x8*)&Q[(q0w + lr)*D_ + 32 + quad*8];

  const f32x4 fz = {0.f,0.f,0.f,0.f};
  f32x4 o[4]; float l_part[4];
  #pragma unroll
  for (int i = 0; i < 4; ++i) { o[i] = fz; l_part[i] = 0.f; }

  float s_h = 1024.f / (1.f + __expf(-sp[h]));
  int kmin = (int)floorf((float)q0w - 33.0f - s_h) + 1;  // first maybe-alive key
  int kt0 = kmin > 0 ? (kmin >> 7) : 0;
  const int ktlast = (q0w + 15) >> 7;
  const float s2 = 0.18033688011112042f;     // log2(e)/sqrt(64)

  for (int kt = kt0; kt <= ktlast; ++kt) {
    const int kb = kt * 128;
    f32x4 sacc[8];
    #pragma unroll
    for (int ni = 0; ni < 8; ++ni) {
      bf16x8 bk0 = *(const bf16x8*)&Km[(kb + ni*16 + lr)*D_ + quad*8];
      bf16x8 bk1 = *(const bf16x8*)&Km[(kb + ni*16 + lr)*D_ + 32 + quad*8];
      sacc[ni] = MFMA16(aq0, bk0, fz);
      sacc[ni] = MFMA16(aq1, bk1, sacc[ni]);
    }
    #pragma unroll
    for (int ni = 0; ni < 8; ++ni) {
      int kg = kb + ni*16 + lr;
      #pragma unroll
      for (int r = 0; r < 4; ++r) {
        int idx = (q0w + quad*4 + r) - kg + 128;      // in [1,1151]
        float tt = fmaf(sacc[ni][r], s2, lm_s[idx]);
        float p;
        asm("v_exp_f32 %0, %1" : "=v"(p) : "v"(tt));  // 2^tt; dead -> 0
        l_part[r] += p;
        p_s[(quad*4 + r)*136 + ni*16 + lr] = (__bf16)p;
      }
    }
    asm volatile("s_waitcnt lgkmcnt(0)" ::: "memory"); // P visible (same wave)
    bf16x8 ap[4];
    #pragma unroll
    for (int sg = 0; sg < 4; ++sg)
      ap[sg] = *(const bf16x8*)&p_s[lr*136 + sg*32 + quad*8];
    #pragma unroll
    for (int ni = 0; ni < 4; ++ni) {
      #pragma unroll
      for (int sg = 0; sg < 4; ++sg) {
        bf16x8 bv = *(const bf16x8*)&Vt[(ni*16 + lr)*T_ + kb + sg*32 + quad*8];
        o[ni] = MFMA16(ap[sg], bv, o[ni]);
      }
    }
    asm volatile("s_waitcnt lgkmcnt(0)" ::: "memory"); // P reads done before overwrite
  }

  // single final row-sum reduction (16 lanes of same quad hold one row)
  #pragma unroll
  for (int off = 1; off < 16; off <<= 1)
    #pragma unroll
    for (int r = 0; r < 4; ++r)
      l_part[r] += __shfl_xor(l_part[r], off, 64);

  #pragma unroll
  for (int ni = 0; ni < 4; ++ni)
    #pragma unroll
    for (int r = 0; r < 4; ++r) {
      int qg = q0w + quad*4 + r;
      float v = o[ni][r] / l_part[r];
      yatt[((size_t)(b*T_ + qg))*C_ + h*D_ + ni*16 + lr] = (__bf16)v;
    }
}

// ---------------------------------------------------------------------------
extern "C" void kernel_launch(void* const* d_in, const int* in_sizes, int n_in,
                              void* d_out, int out_size, void* d_ws, size_t ws_size,
                              hipStream_t stream) {
  const float* x     = (const float*)d_in[0];
  const float* Wqkv  = (const float*)d_in[1];
  const float* Wproj = (const float*)d_in[2];
  const float* sp    = (const float*)d_in[3];
  const float* pw    = (const float*)d_in[4];
  const float* rw    = (const float*)d_in[5];
  float* out = (float*)d_out;

  char* ws = (char*)d_ws;
  size_t off = 0;
  auto alloc = [&](size_t bytes) -> void* {
    void* p = ws + off;
    off += (bytes + 255) & ~(size_t)255;
    return p;
  };
  float*  LM     = (float*) alloc((size_t)H_*T_*4);
  __bf16* wqkv_t = (__bf16*)alloc((size_t)3*C_*C_*2);
  __bf16* wp_t   = (__bf16*)alloc((size_t)C_*C_*2);
  __bf16* q_bf   = (__bf16*)alloc((size_t)B_*H_*T_*D_*2);
  __bf16* k_bf   = (__bf16*)alloc((size_t)B_*H_*T_*D_*2);
  __bf16* vt_bf  = (__bf16*)alloc((size_t)B_*H_*T_*D_*2);
  __bf16* yatt   = (__bf16*)alloc((size_t)B_*T_*C_*2);
  __bf16* x_bf   = yatt;   // aliased: x_bf dead before attn writes yatt

  lm_kernel<<<H_, 256, 0, stream>>>(sp, pw, rw, LM, out + (out_size - 1));
  transpose_cvt<<<dim3(3*C_/64, C_/64), 256, 0, stream>>>(Wqkv, wqkv_t, C_, 3*C_);
  transpose_cvt<<<dim3(C_/64,   C_/64), 256, 0, stream>>>(Wproj, wp_t, C_, C_);
  cvt_kernel<<<(B_*T_*C_)/(256*8), 256, 0, stream>>>(x, x_bf);
  gemm_bt<0><<<dim3(3*C_/128, (B_*T_)/128), 256, 0, stream>>>(
      x_bf, wqkv_t, B_*T_, 3*C_, C_, q_bf, k_bf, vt_bf, nullptr);
  attn_kernel<<<dim3(B_*H_, T_/16), 64, 0, stream>>>(q_bf, k_bf, vt_bf, LM, sp, yatt);
  gemm_bt<1><<<dim3(C_/128, (B_*T_)/128), 256, 0, stream>>>(
      yatt, wp_t, B_*T_, C_, C_, nullptr, nullptr, nullptr, out);
}